// Round 4
// baseline (8103.550 us; speedup 1.0000x reference)
//
#include <hip/hip_runtime.h>
#include <hip/hip_bf16.h>

#define NROWS   32768          // 32*16*64 rows of dim 64
#define NCODE   8192
#define NSPLIT  4              // code-dimension splits for occupancy
#define CSPLIT  (NCODE / NSPLIT)

// d_out element offsets (FLOAT32 elements):
// quantize(2097152), ind(32768), loss(1), cluster(8192), eavg(524288), embed(524288)
#define OUT_Q        0
#define OUT_IND      2097152
#define OUT_LOSS     2129920
#define OUT_CLUSTER  2129921
#define OUT_EAVG     2138113
#define OUT_EMBED    2662401

// workspace byte offsets — total ~3.5 MB
#define WS_LOSS     0            // f32 [1] (zeroed)
#define WS_TOTAL    4            // f32 [1] (zeroed)
#define WS_SE       64           // f32 [8192]  ||e_j||^2
#define WS_COUNTS   32832        // f32 [8192]  (zeroed)
#define WS_IND      65600        // i32 [32768]
#define WS_ESUM     196672       // f32 [64*8192] (zeroed)
#define WS_PBEST    2293824      // f32 [4*32768] partial best dist
#define WS_PIDX     2818112      // i32 [4*32768] partial best idx
// end: 3,342,400 bytes

__device__ __forceinline__ int pos_off(int c, int R, int k) {
    // pos_emb[(R>>2)*16 + (k>>2)][c*16 + (R&3)*4 + (k&3)], row stride 256
    return (((R >> 2) * 16 + (k >> 2)) << 8) + (c << 4) + ((R & 3) << 2) + (k & 3);
}

// ---------------- K0: init ind=0 and compute ||e_j||^2 --------------------
__global__ __launch_bounds__(256) void k_prep(
    const float* __restrict__ embed, float* __restrict__ se, int* __restrict__ ind)
{
    const int t = blockIdx.x * 256 + threadIdx.x;   // 128 blocks -> 0..32767
    ind[t] = 0;
    if (t < NCODE) {
        float s = 0.f;
#pragma unroll
        for (int k = 0; k < 64; ++k) {
            float v = embed[(size_t)k * NCODE + t];
            s = fmaf(v, v, s);
        }
        se[t] = s;
    }
}

// ---------------- K1: fp32 GEMM-argmin, split-K over codes ----------------
// Grid 2048: blockIdx>>2 = row-block (64 rows), blockIdx&3 = code split (2048).
// Thread: 8 rows x 8 codes. Distance arithmetic identical to the monolithic
// version (same k-chain, same rounding sequence) => bit-identical distances.
__global__ __launch_bounds__(256, 8) void k_argmin_split(
    const float* __restrict__ x, const float* __restrict__ pos,
    const float* __restrict__ embed, const float* __restrict__ s_e,
    float* __restrict__ part_best, int* __restrict__ part_idx)
{
    __shared__ __align__(16) float xT[64 * 68];   // xT[k][row], stride 68
    __shared__ float sx[64];                      // ||x_row||^2
    const int tid = threadIdx.x;
    const int row0  = (blockIdx.x >> 2) * 64;
    const int split = blockIdx.x & 3;
    const int rg = tid >> 5;                      // 0..7 (8 rows each)
    const int cg = tid & 31;                      // 0..31 (8 codes each)

    // stage q = x + pos into LDS transposed
#pragma unroll
    for (int p = 0; p < 16; ++p) {
        int idx = p * 256 + tid;                  // 0..4095
        int rr = idx >> 6, k = idx & 63;
        int n = row0 + rr;
        int c = (n >> 6) & 15, R = n & 63;
        float v = x[(size_t)n * 64 + k] + pos[pos_off(c, R, k)];
        xT[k * 68 + rr] = v;
    }
    __syncthreads();
    if (tid < 64) {                               // row norms
        float s = 0.f;
#pragma unroll
        for (int k = 0; k < 64; ++k) { float v = xT[k * 68 + tid]; s = fmaf(v, v, s); }
        sx[tid] = s;
    }
    __syncthreads();

    float best[8];
    int   bidx[8];
#pragma unroll
    for (int r = 0; r < 8; ++r) { best[r] = 3.402823466e38f; bidx[r] = 0; }
    float sxr[8];
#pragma unroll
    for (int r = 0; r < 8; ++r) sxr[r] = sx[rg * 8 + r];

    const int xoff = rg * 8;
    const int jbeg = split * CSPLIT;
    for (int jt = jbeg; jt < jbeg + CSPLIT; jt += 256) {
        const int j0 = jt + cg * 8;
        float acc[8][8];
#pragma unroll
        for (int r = 0; r < 8; ++r)
#pragma unroll
            for (int c = 0; c < 8; ++c) acc[r][c] = 0.f;

#pragma unroll 4
        for (int k = 0; k < 64; ++k) {
            const float4 xa = *(const float4*)(xT + k * 68 + xoff);
            const float4 xb = *(const float4*)(xT + k * 68 + xoff + 4);
            const float4 e0 = *(const float4*)(embed + (size_t)k * NCODE + j0);
            const float4 e1 = *(const float4*)(embed + (size_t)k * NCODE + j0 + 4);
            float xs[8] = {xa.x, xa.y, xa.z, xa.w, xb.x, xb.y, xb.z, xb.w};
            float es[8] = {e0.x, e0.y, e0.z, e0.w, e1.x, e1.y, e1.z, e1.w};
#pragma unroll
            for (int r = 0; r < 8; ++r)
#pragma unroll
                for (int c = 0; c < 8; ++c)
                    acc[r][c] = fmaf(xs[r], es[c], acc[r][c]);
        }

        const float4 sa = *(const float4*)(s_e + j0);
        const float4 sb = *(const float4*)(s_e + j0 + 4);
        float ss[8] = {sa.x, sa.y, sa.z, sa.w, sb.x, sb.y, sb.z, sb.w};
#pragma unroll
        for (int c = 0; c < 8; ++c) {
            const int j = j0 + c;
#pragma unroll
            for (int r = 0; r < 8; ++r) {
                float t = sxr[r] - 2.0f * acc[r][c];   // np rounding sequence
                float d = t + ss[c];
                if (d < best[r]) { best[r] = d; bidx[r] = j; }
            }
        }
    }

    // reduce across the 32 code-groups
#pragma unroll
    for (int r = 0; r < 8; ++r) {
        float bv = best[r]; int bi = bidx[r];
#pragma unroll
        for (int m = 16; m >= 1; m >>= 1) {
            float ov = __shfl_xor(bv, m, 64);
            int   oi = __shfl_xor(bi, m, 64);
            if (ov < bv || (ov == bv && oi < bi)) { bv = ov; bi = oi; }
        }
        if (cg == 0) {
            int row = row0 + rg * 8 + r;
            part_best[split * NROWS + row] = bv;
            part_idx [split * NROWS + row] = bi;
        }
    }
}

// ---------------- K1b: merge the 4 split partials -------------------------
__global__ __launch_bounds__(256) void k_reduce(
    const float* __restrict__ part_best, const int* __restrict__ part_idx,
    int* __restrict__ ind, float* __restrict__ out_ind)
{
    const int n = blockIdx.x * 256 + threadIdx.x;   // 128 blocks
    float bv = part_best[n];
    int   bi = part_idx[n];
#pragma unroll
    for (int s = 1; s < NSPLIT; ++s) {
        float v = part_best[s * NROWS + n];
        int   i = part_idx [s * NROWS + n];
        if (v < bv || (v == bv && i < bi)) { bv = v; bi = i; }  // lower idx wins ties
    }
    ind[n] = bi;
    out_ind[n] = (float)bi;
}

// ---------------- K2: quantize gather + loss + EMA scatter ----------------
__global__ __launch_bounds__(256) void k_quant(
    const float* __restrict__ x, const float* __restrict__ pos,
    const float* __restrict__ embed, const int* __restrict__ ind,
    float* __restrict__ embed_sum, float* __restrict__ counts,
    float* __restrict__ loss_ws, float* __restrict__ out_q)
{
    const int tid = threadIdx.x;
    const int rr = tid >> 6, k = tid & 63;       // 4 rows x 64 dims
    const int n = blockIdx.x * 4 + rr;
    int idx = ind[n];
    idx = idx < 0 ? 0 : (idx > NCODE - 1 ? NCODE - 1 : idx);  // defensive clamp
    const float qv = embed[(size_t)k * NCODE + idx];
    const float xv = x[(size_t)n * 64 + k];
    out_q[(size_t)n * 64 + k] = qv;

    const int c = (n >> 6) & 15, R = n & 63;
    const float fv = xv + pos[pos_off(c, R, k)];
    atomicAdd(&embed_sum[(size_t)k * NCODE + idx], fv);
    if (k == 0) atomicAdd(&counts[idx], 1.0f);

    float sq = (qv - xv) * (qv - xv);
#pragma unroll
    for (int m = 32; m >= 1; m >>= 1) sq += __shfl_xor(sq, m, 64);
    __shared__ float ls[4];
    if ((tid & 63) == 0) ls[tid >> 6] = sq;
    __syncthreads();
    if (tid == 0) atomicAdd(loss_ws, ls[0] + ls[1] + ls[2] + ls[3]);
}

// ---------------- K3a: new_cluster + total --------------------------------
__global__ __launch_bounds__(256) void k_final1(
    const float* __restrict__ cluster, const float* __restrict__ counts,
    float* __restrict__ total_ws, float* __restrict__ out_cluster)
{
    const int j = blockIdx.x * 256 + threadIdx.x;   // 32 blocks
    float nc = 0.8f * cluster[j] + 0.2f * counts[j];
    out_cluster[j] = nc;
    float s = nc;
#pragma unroll
    for (int m = 32; m >= 1; m >>= 1) s += __shfl_xor(s, m, 64);
    __shared__ float ls[4];
    if ((threadIdx.x & 63) == 0) ls[threadIdx.x >> 6] = s;
    __syncthreads();
    if (threadIdx.x == 0) atomicAdd(total_ws, ls[0] + ls[1] + ls[2] + ls[3]);
}

// ---------------- K3b: smoothed / new_embed_avg / new_embed / loss --------
__global__ __launch_bounds__(256) void k_final2(
    const float* __restrict__ cluster, const float* __restrict__ counts,
    const float* __restrict__ embed_avg, const float* __restrict__ embed_sum,
    const float* __restrict__ total_ws, const float* __restrict__ loss_ws,
    float* __restrict__ out_loss, float* __restrict__ out_eavg,
    float* __restrict__ out_embed)
{
    const int e = blockIdx.x * 256 + threadIdx.x;   // 2048 blocks -> 524288
    const int j = e & (NCODE - 1);
    const float total = *total_ws;
    float nc = 0.8f * cluster[j] + 0.2f * counts[j];
    float smoothed = (nc + 1e-5f) / (total + 0.08192f) * total;
    float ea = 0.8f * embed_avg[e] + 0.2f * embed_sum[e];
    out_eavg[e]  = ea;
    out_embed[e] = ea / smoothed;
    if (e == 0) *out_loss = *loss_ws * (1.0f / 2097152.0f);
}

extern "C" void kernel_launch(void* const* d_in, const int* in_sizes, int n_in,
                              void* d_out, int out_size, void* d_ws, size_t ws_size,
                              hipStream_t stream) {
    (void)in_sizes; (void)n_in; (void)out_size; (void)ws_size;
    const float* x        = (const float*)d_in[0];   // (32,16,64,64)
    const float* embed    = (const float*)d_in[1];   // (64,8192)
    const float* pos      = (const float*)d_in[2];   // (2048,256)
    const float* cluster  = (const float*)d_in[3];   // (8192,)
    const float* eavg     = (const float*)d_in[4];   // (64,8192)
    float* out = (float*)d_out;                      // fp32 outputs, concatenated

    char* ws = (char*)d_ws;
    float* w_loss   = (float*)(ws + WS_LOSS);
    float* w_total  = (float*)(ws + WS_TOTAL);
    float* w_se     = (float*)(ws + WS_SE);
    float* w_counts = (float*)(ws + WS_COUNTS);
    int*   w_ind    = (int*)  (ws + WS_IND);
    float* w_esum   = (float*)(ws + WS_ESUM);
    float* w_pbest  = (float*)(ws + WS_PBEST);
    int*   w_pidx   = (int*)  (ws + WS_PIDX);

    // zero accumulators (ws is poisoned 0xAA before every launch)
    hipMemsetAsync(ws + WS_LOSS,   0, 8, stream);
    hipMemsetAsync(ws + WS_COUNTS, 0, 32768, stream);
    hipMemsetAsync(ws + WS_ESUM,   0, 2097152, stream);

    k_prep<<<128, 256, 0, stream>>>(embed, w_se, w_ind);
    k_argmin_split<<<(NROWS / 64) * NSPLIT, 256, 0, stream>>>(
        x, pos, embed, w_se, w_pbest, w_pidx);
    k_reduce<<<NROWS / 256, 256, 0, stream>>>(w_pbest, w_pidx, w_ind,
                                              out + OUT_IND);
    k_quant<<<NROWS / 4, 256, 0, stream>>>(x, pos, embed, w_ind, w_esum,
                                           w_counts, w_loss, out + OUT_Q);
    k_final1<<<NCODE / 256, 256, 0, stream>>>(cluster, w_counts, w_total,
                                              out + OUT_CLUSTER);
    k_final2<<<524288 / 256, 256, 0, stream>>>(cluster, w_counts, eavg, w_esum,
                                               w_total, w_loss, out + OUT_LOSS,
                                               out + OUT_EAVG, out + OUT_EMBED);
}

// Round 5
// 709.527 us; speedup vs baseline: 11.4211x; 11.4211x over previous
//
#include <hip/hip_runtime.h>
#include <hip/hip_bf16.h>

#define NROWS   32768          // 32*16*64 rows of dim 64
#define NCODE   8192
#define NSPLIT  4              // code-dimension splits for occupancy
#define CSPLIT  (NCODE / NSPLIT)

// d_out element offsets (FLOAT32 elements):
// quantize(2097152), ind(32768), loss(1), cluster(8192), eavg(524288), embed(524288)
#define OUT_Q        0
#define OUT_IND      2097152
#define OUT_LOSS     2129920
#define OUT_CLUSTER  2129921
#define OUT_EAVG     2138113
#define OUT_EMBED    2662401

// workspace byte offsets — total ~3.5 MB
#define WS_LOSS     0            // f32 [1] (zeroed)
#define WS_TOTAL    4            // f32 [1] (zeroed)
#define WS_SE       64           // f32 [8192]  ||e_j||^2
#define WS_COUNTS   32832        // f32 [8192]  (zeroed)
#define WS_IND      65600        // i32 [32768]
#define WS_ESUM     196672       // f32 [64*8192] (zeroed)
#define WS_PBEST    2293824      // f32 [4*32768] partial best dist
#define WS_PIDX     2818112      // i32 [4*32768] partial best idx
// end: 3,342,400 bytes

__device__ __forceinline__ int pos_off(int c, int R, int k) {
    // pos_emb[(R>>2)*16 + (k>>2)][c*16 + (R&3)*4 + (k&3)], row stride 256
    return (((R >> 2) * 16 + (k >> 2)) << 8) + (c << 4) + ((R & 3) << 2) + (k & 3);
}

// ---------------- K0: init ind=0 and compute ||e_j||^2 --------------------
__global__ __launch_bounds__(256) void k_prep(
    const float* __restrict__ embed, float* __restrict__ se, int* __restrict__ ind)
{
    const int t = blockIdx.x * 256 + threadIdx.x;   // 128 blocks -> 0..32767
    ind[t] = 0;
    if (t < NCODE) {
        float s = 0.f;
#pragma unroll
        for (int k = 0; k < 64; ++k) {
            float v = embed[(size_t)k * NCODE + t];
            s = fmaf(v, v, s);
        }
        se[t] = s;
    }
}

// ---------------- K1: fp32 GEMM-argmin, split over codes ------------------
// Grid 2048: blockIdx>>2 = row-block (64 rows), blockIdx&3 = code split (2048).
// Thread: 8 rows x 8 codes. NOTE: plain __launch_bounds__(256) — the (256,8)
// variant capped regs at 32 and spilled acc[8][8] to scratch (40 GB traffic,
// 10x regression, R4). Accumulator lives in AGPRs; ~128 regs/lane total
// => 4 waves/SIMD (50% occupancy) is the hardware ceiling here.
__global__ __launch_bounds__(256) void k_argmin_split(
    const float* __restrict__ x, const float* __restrict__ pos,
    const float* __restrict__ embed, const float* __restrict__ s_e,
    float* __restrict__ part_best, int* __restrict__ part_idx)
{
    __shared__ __align__(16) float xT[64 * 68];   // xT[k][row], stride 68
    __shared__ float sx[64];                      // ||x_row||^2
    const int tid = threadIdx.x;
    const int row0  = (blockIdx.x >> 2) * 64;
    const int split = blockIdx.x & 3;
    const int rg = tid >> 5;                      // 0..7 (8 rows each)
    const int cg = tid & 31;                      // 0..31 (8 codes each)

    // stage q = x + pos into LDS transposed
#pragma unroll
    for (int p = 0; p < 16; ++p) {
        int idx = p * 256 + tid;                  // 0..4095
        int rr = idx >> 6, k = idx & 63;
        int n = row0 + rr;
        int c = (n >> 6) & 15, R = n & 63;
        float v = x[(size_t)n * 64 + k] + pos[pos_off(c, R, k)];
        xT[k * 68 + rr] = v;
    }
    __syncthreads();
    if (tid < 64) {                               // row norms
        float s = 0.f;
#pragma unroll
        for (int k = 0; k < 64; ++k) { float v = xT[k * 68 + tid]; s = fmaf(v, v, s); }
        sx[tid] = s;
    }
    __syncthreads();

    float best[8];
    int   bidx[8];
#pragma unroll
    for (int r = 0; r < 8; ++r) { best[r] = 3.402823466e38f; bidx[r] = 0; }
    float sxr[8];
#pragma unroll
    for (int r = 0; r < 8; ++r) sxr[r] = sx[rg * 8 + r];

    const int xoff = rg * 8;
    const int jbeg = split * CSPLIT;
    for (int jt = jbeg; jt < jbeg + CSPLIT; jt += 256) {
        const int j0 = jt + cg * 8;
        float acc[8][8];
#pragma unroll
        for (int r = 0; r < 8; ++r)
#pragma unroll
            for (int c = 0; c < 8; ++c) acc[r][c] = 0.f;

#pragma unroll 4
        for (int k = 0; k < 64; ++k) {
            const float4 xa = *(const float4*)(xT + k * 68 + xoff);
            const float4 xb = *(const float4*)(xT + k * 68 + xoff + 4);
            const float4 e0 = *(const float4*)(embed + (size_t)k * NCODE + j0);
            const float4 e1 = *(const float4*)(embed + (size_t)k * NCODE + j0 + 4);
            float xs[8] = {xa.x, xa.y, xa.z, xa.w, xb.x, xb.y, xb.z, xb.w};
            float es[8] = {e0.x, e0.y, e0.z, e0.w, e1.x, e1.y, e1.z, e1.w};
#pragma unroll
            for (int r = 0; r < 8; ++r)
#pragma unroll
                for (int c = 0; c < 8; ++c)
                    acc[r][c] = fmaf(xs[r], es[c], acc[r][c]);
        }

        const float4 sa = *(const float4*)(s_e + j0);
        const float4 sb = *(const float4*)(s_e + j0 + 4);
        float ss[8] = {sa.x, sa.y, sa.z, sa.w, sb.x, sb.y, sb.z, sb.w};
#pragma unroll
        for (int c = 0; c < 8; ++c) {
            const int j = j0 + c;
#pragma unroll
            for (int r = 0; r < 8; ++r) {
                float t = sxr[r] - 2.0f * acc[r][c];   // np rounding sequence
                float d = t + ss[c];
                if (d < best[r]) { best[r] = d; bidx[r] = j; }
            }
        }
    }

    // reduce across the 32 code-groups
#pragma unroll
    for (int r = 0; r < 8; ++r) {
        float bv = best[r]; int bi = bidx[r];
#pragma unroll
        for (int m = 16; m >= 1; m >>= 1) {
            float ov = __shfl_xor(bv, m, 64);
            int   oi = __shfl_xor(bi, m, 64);
            if (ov < bv || (ov == bv && oi < bi)) { bv = ov; bi = oi; }
        }
        if (cg == 0) {
            int row = row0 + rg * 8 + r;
            part_best[split * NROWS + row] = bv;
            part_idx [split * NROWS + row] = bi;
        }
    }
}

// ---------------- K1b: merge the 4 split partials -------------------------
__global__ __launch_bounds__(256) void k_reduce(
    const float* __restrict__ part_best, const int* __restrict__ part_idx,
    int* __restrict__ ind, float* __restrict__ out_ind)
{
    const int n = blockIdx.x * 256 + threadIdx.x;   // 128 blocks
    float bv = part_best[n];
    int   bi = part_idx[n];
#pragma unroll
    for (int s = 1; s < NSPLIT; ++s) {
        float v = part_best[s * NROWS + n];
        int   i = part_idx [s * NROWS + n];
        if (v < bv || (v == bv && i < bi)) { bv = v; bi = i; }  // lower idx wins ties
    }
    ind[n] = bi;
    out_ind[n] = (float)bi;
}

// ---------------- K2: quantize gather + loss + EMA scatter ----------------
__global__ __launch_bounds__(256) void k_quant(
    const float* __restrict__ x, const float* __restrict__ pos,
    const float* __restrict__ embed, const int* __restrict__ ind,
    float* __restrict__ embed_sum, float* __restrict__ counts,
    float* __restrict__ loss_ws, float* __restrict__ out_q)
{
    const int tid = threadIdx.x;
    const int rr = tid >> 6, k = tid & 63;       // 4 rows x 64 dims
    const int n = blockIdx.x * 4 + rr;
    int idx = ind[n];
    idx = idx < 0 ? 0 : (idx > NCODE - 1 ? NCODE - 1 : idx);  // defensive clamp
    const float qv = embed[(size_t)k * NCODE + idx];
    const float xv = x[(size_t)n * 64 + k];
    out_q[(size_t)n * 64 + k] = qv;

    const int c = (n >> 6) & 15, R = n & 63;
    const float fv = xv + pos[pos_off(c, R, k)];
    atomicAdd(&embed_sum[(size_t)k * NCODE + idx], fv);
    if (k == 0) atomicAdd(&counts[idx], 1.0f);

    float sq = (qv - xv) * (qv - xv);
#pragma unroll
    for (int m = 32; m >= 1; m >>= 1) sq += __shfl_xor(sq, m, 64);
    __shared__ float ls[4];
    if ((tid & 63) == 0) ls[tid >> 6] = sq;
    __syncthreads();
    if (tid == 0) atomicAdd(loss_ws, ls[0] + ls[1] + ls[2] + ls[3]);
}

// ---------------- K3a: new_cluster + total --------------------------------
__global__ __launch_bounds__(256) void k_final1(
    const float* __restrict__ cluster, const float* __restrict__ counts,
    float* __restrict__ total_ws, float* __restrict__ out_cluster)
{
    const int j = blockIdx.x * 256 + threadIdx.x;   // 32 blocks
    float nc = 0.8f * cluster[j] + 0.2f * counts[j];
    out_cluster[j] = nc;
    float s = nc;
#pragma unroll
    for (int m = 32; m >= 1; m >>= 1) s += __shfl_xor(s, m, 64);
    __shared__ float ls[4];
    if ((threadIdx.x & 63) == 0) ls[threadIdx.x >> 6] = s;
    __syncthreads();
    if (threadIdx.x == 0) atomicAdd(total_ws, ls[0] + ls[1] + ls[2] + ls[3]);
}

// ---------------- K3b: smoothed / new_embed_avg / new_embed / loss --------
__global__ __launch_bounds__(256) void k_final2(
    const float* __restrict__ cluster, const float* __restrict__ counts,
    const float* __restrict__ embed_avg, const float* __restrict__ embed_sum,
    const float* __restrict__ total_ws, const float* __restrict__ loss_ws,
    float* __restrict__ out_loss, float* __restrict__ out_eavg,
    float* __restrict__ out_embed)
{
    const int e = blockIdx.x * 256 + threadIdx.x;   // 2048 blocks -> 524288
    const int j = e & (NCODE - 1);
    const float total = *total_ws;
    float nc = 0.8f * cluster[j] + 0.2f * counts[j];
    float smoothed = (nc + 1e-5f) / (total + 0.08192f) * total;
    float ea = 0.8f * embed_avg[e] + 0.2f * embed_sum[e];
    out_eavg[e]  = ea;
    out_embed[e] = ea / smoothed;
    if (e == 0) *out_loss = *loss_ws * (1.0f / 2097152.0f);
}

extern "C" void kernel_launch(void* const* d_in, const int* in_sizes, int n_in,
                              void* d_out, int out_size, void* d_ws, size_t ws_size,
                              hipStream_t stream) {
    (void)in_sizes; (void)n_in; (void)out_size; (void)ws_size;
    const float* x        = (const float*)d_in[0];   // (32,16,64,64)
    const float* embed    = (const float*)d_in[1];   // (64,8192)
    const float* pos      = (const float*)d_in[2];   // (2048,256)
    const float* cluster  = (const float*)d_in[3];   // (8192,)
    const float* eavg     = (const float*)d_in[4];   // (64,8192)
    float* out = (float*)d_out;                      // fp32 outputs, concatenated

    char* ws = (char*)d_ws;
    float* w_loss   = (float*)(ws + WS_LOSS);
    float* w_total  = (float*)(ws + WS_TOTAL);
    float* w_se     = (float*)(ws + WS_SE);
    float* w_counts = (float*)(ws + WS_COUNTS);
    int*   w_ind    = (int*)  (ws + WS_IND);
    float* w_esum   = (float*)(ws + WS_ESUM);
    float* w_pbest  = (float*)(ws + WS_PBEST);
    int*   w_pidx   = (int*)  (ws + WS_PIDX);

    // zero accumulators (ws is poisoned 0xAA before every launch)
    hipMemsetAsync(ws + WS_LOSS,   0, 8, stream);
    hipMemsetAsync(ws + WS_COUNTS, 0, 32768, stream);
    hipMemsetAsync(ws + WS_ESUM,   0, 2097152, stream);

    k_prep<<<128, 256, 0, stream>>>(embed, w_se, w_ind);
    k_argmin_split<<<(NROWS / 64) * NSPLIT, 256, 0, stream>>>(
        x, pos, embed, w_se, w_pbest, w_pidx);
    k_reduce<<<NROWS / 256, 256, 0, stream>>>(w_pbest, w_pidx, w_ind,
                                              out + OUT_IND);
    k_quant<<<NROWS / 4, 256, 0, stream>>>(x, pos, embed, w_ind, w_esum,
                                           w_counts, w_loss, out + OUT_Q);
    k_final1<<<NCODE / 256, 256, 0, stream>>>(cluster, w_counts, w_total,
                                              out + OUT_CLUSTER);
    k_final2<<<524288 / 256, 256, 0, stream>>>(cluster, w_counts, eavg, w_esum,
                                               w_total, w_loss, out + OUT_LOSS,
                                               out + OUT_EAVG, out + OUT_EMBED);
}